// Round 15
// baseline (76.220 us; speedup 1.0000x reference)
//
#include <hip/hip_runtime.h>
#include <stdint.h>

#define HID 1024
#define BB 4
#define TT 2048
#define M_ROWS (BB * TT)  // 8192

typedef __attribute__((ext_vector_type(8))) short s16x8;
typedef __attribute__((ext_vector_type(4))) float f32x4;

__device__ __forceinline__ unsigned short f2bf(float f) {
  unsigned u = __float_as_uint(f);
  u += 0x7fffu + ((u >> 16) & 1u);  // RNE
  return (unsigned short)(u >> 16);
}

__device__ __forceinline__ s16x8 cvt8(float4 a, float4 b) {
  s16x8 v;
  v[0] = (short)f2bf(a.x); v[1] = (short)f2bf(a.y); v[2] = (short)f2bf(a.z); v[3] = (short)f2bf(a.w);
  v[4] = (short)f2bf(b.x); v[5] = (short)f2bf(b.y); v[6] = (short)f2bf(b.z); v[7] = (short)f2bf(b.w);
  return v;
}

__device__ __forceinline__ void gload16(const void* g, void* l) {
  __builtin_amdgcn_global_load_lds(
      (const __attribute__((address_space(1))) unsigned int*)g,
      (__attribute__((address_space(3))) unsigned int*)l, 16, 0, 0);
}

// ------- weight prep: z=0 transpose Wv [in][out] -> bf16 [out][in]; z=1 cvt Wo -------
__global__ void prep_weights(const float* __restrict__ Wv, const float* __restrict__ Wo,
                             unsigned short* __restrict__ wvt, unsigned short* __restrict__ wob) {
  int tx = threadIdx.x, ty = threadIdx.y;
  int i0 = blockIdx.y * 32, o0 = blockIdx.x * 32;
  if (blockIdx.z == 1) {
#pragma unroll
    for (int k = 0; k < 4; ++k)
      wob[(size_t)(i0 + ty + 8 * k) * HID + o0 + tx] = f2bf(Wo[(size_t)(i0 + ty + 8 * k) * HID + o0 + tx]);
    return;
  }
  __shared__ float tile[32][33];
#pragma unroll
  for (int k = 0; k < 4; ++k)
    tile[ty + 8 * k][tx] = Wv[(size_t)(i0 + ty + 8 * k) * HID + o0 + tx];
  __syncthreads();
#pragma unroll
  for (int k = 0; k < 4; ++k)
    wvt[(size_t)(o0 + ty + 8 * k) * HID + i0 + tx] = f2bf(tile[tx][ty + 8 * k]);
}

// ======== BK=32 wide-wave GEMM: C[M,N] = A[M,K] * Bt[N,K]^T ========
// BM=BN=128, BK=32, 256 thr (4 waves 2Mx2N), per-wave 64x64 (acc 4x4, 16 MFMA/tile).
// LDS-instr ratio 0.625/MFMA (8 frag reads + 2 writes per 16 MFMA) vs 0.875 before.
// A (MODE 0): x fp32 reg-staged + cvt, manual ds_write into PADDED [128][40] rows
//   (80B stride -> frag reads max 2-way conflict = free; padding legal since writes
//   are manual, not gload_lds).
// A (MODE 1): bf16 via gload_lds, linear [128][32] + 2-bit slot-xor swizzle.
// B: bf16 via gload_lds, linear [128][32] + 2-bit slot-xor swizzle.
// Ring-2 both; one __syncthreads per K-tile; 36 KB LDS/block -> 3+ blocks/CU
// co-resident (m114 overlap hides barrier drain). T1 XCD-bijective block swizzle.
// MODE 0: out bf16 scattered to the permuted ctx layout (einsum collapse).
// MODE 1: out fp32 row-major.
#define APAD 40  // shorts per A row (MODE 0); 80B stride
template <int MODE>
__global__ __launch_bounds__(256, 2) void gemm_bk32(const void* __restrict__ Av,
                                                    const unsigned short* __restrict__ Bt,
                                                    void* __restrict__ outBase) {
  constexpr int Kd = 1024;
  constexpr int NT = 32;  // K-tiles of 32
  const int tid = threadIdx.x;
  const int lane = tid & 63;
  const int w = tid >> 6;
  const int wm = w >> 1, wn = w & 1;
  const int lr = lane & 15, lg = lane >> 4;
  const int lin = blockIdx.x;
  const int wid = (lin & 7) * 64 + (lin >> 3);  // XCD-bijective (512 = 8x64)
  const int blockM = (wid >> 3) * 128;
  const int blockN = (wid & 7) * 128;

  // MODE 0: padded A; MODE 1: linear A. B always linear.
  __shared__ __align__(16) short Abuf[2][MODE == 0 ? 128 * APAD : 128 * 32];
  __shared__ __align__(16) short Bbuf[2][128 * 32];

  f32x4 acc[4][4] = {};
  const float* Af32 = (const float*)Av;
  const unsigned short* Ab16 = (const unsigned short*)Av;
  const unsigned short* pb = Bt + (size_t)blockN * Kd;

  // ---- staging maps ----
  // gload_lds granule: pass p, lane-linear g = p*256 + tid; row = g>>2, slot = g&3.
  // LDS linear (row, slot) <- global (row, slot ^ swz(row)), swz(r) = (r ^ (r>>2)) & 3.
  const int sw = (((tid >> 2) ^ (tid >> 4)) & 3);       // swz(row) is pass-invariant
  const int sgx = (((tid & 3) ^ sw) * 8);               // source slot offset (shorts)
  const int grow = tid >> 2;                            // row within pass (0..63)

  auto stageB = [&](int bi, int kt) {
    gload16(pb + (size_t)grow * Kd + kt * 32 + sgx, (char*)Bbuf[bi] + (size_t)(w * 64) * 16);
    gload16(pb + (size_t)(64 + grow) * Kd + kt * 32 + sgx,
            (char*)Bbuf[bi] + (size_t)(256 + w * 64) * 16);
  };
  auto stageA16 = [&](int bi, int kt) {
    gload16(Ab16 + (size_t)(blockM + grow) * Kd + kt * 32 + sgx,
            (char*)Abuf[bi] + (size_t)(w * 64) * 16);
    gload16(Ab16 + (size_t)(blockM + 64 + grow) * Kd + kt * 32 + sgx,
            (char*)Abuf[bi] + (size_t)(256 + w * 64) * 16);
  };

  // MODE 0 A staging: thread -> row tid>>1, col-half tid&1 (16 floats)
  const int arow = tid >> 1;
  const int ahalf = tid & 1;
  float4 areg[4];
  auto loadA32 = [&](int kt) {
    const float* s = Af32 + (size_t)(blockM + arow) * Kd + kt * 32 + ahalf * 16;
    areg[0] = *(const float4*)s;
    areg[1] = *(const float4*)(s + 4);
    areg[2] = *(const float4*)(s + 8);
    areg[3] = *(const float4*)(s + 12);
  };
  auto writeA32 = [&](int bi) {
    short* dst = Abuf[bi] + arow * APAD + ahalf * 16;
    *(s16x8*)(dst) = cvt8(areg[0], areg[1]);
    *(s16x8*)(dst + 8) = cvt8(areg[2], areg[3]);
  };

  // ---- frag-read offsets ----
  const int cB = ((lr ^ (lr >> 2)) & 3);  // swz(row) at frag-read time (row = ..+lr)
  const int bco = ((lg ^ cB) & 3) * 8;    // swizzled k-granule offset for linear bufs

  auto compute = [&](const short* Ab, const short* Bb) {
    s16x8 af[4], bf[4];
#pragma unroll
    for (int mi = 0; mi < 4; ++mi) {
      if constexpr (MODE == 0)
        af[mi] = *(const s16x8*)(Ab + (wm * 64 + mi * 16 + lr) * APAD + lg * 8);
      else
        af[mi] = *(const s16x8*)(Ab + (wm * 64 + mi * 16 + lr) * 32 + bco);
    }
#pragma unroll
    for (int ni = 0; ni < 4; ++ni)
      bf[ni] = *(const s16x8*)(Bb + (wn * 64 + ni * 16 + lr) * 32 + bco);
    __builtin_amdgcn_s_setprio(1);
#pragma unroll
    for (int mi = 0; mi < 4; ++mi)
#pragma unroll
      for (int ni = 0; ni < 4; ++ni)
        acc[mi][ni] = __builtin_amdgcn_mfma_f32_16x16x32_bf16(af[mi], bf[ni], acc[mi][ni], 0, 0, 0);
    __builtin_amdgcn_s_setprio(0);
  };

  // ---- prologue: tile 0 ----
  if constexpr (MODE == 0) {
    loadA32(0);
    stageB(0, 0);
    writeA32(0);
  } else {
    stageA16(0, 0);
    stageB(0, 0);
  }
  __syncthreads();

  for (int t = 0; t < NT; ++t) {
    const int bn = (t + 1) & 1;
    if (t + 1 < NT) {
      if constexpr (MODE == 0) loadA32(t + 1);
      else stageA16(bn, t + 1);
      stageB(bn, t + 1);
    }
    compute(Abuf[t & 1], Bbuf[t & 1]);
    if (t + 1 < NT) {
      if constexpr (MODE == 0) writeA32(bn);
      __syncthreads();
    }
  }

  if constexpr (MODE == 0) {
    // permuted ctx layout (einsum collapse: ctx[b,h,t,d] = v[b,t,h,d])
    unsigned short* out = (unsigned short*)outBase;
#pragma unroll
    for (int mi = 0; mi < 4; ++mi) {
#pragma unroll
      for (int ni = 0; ni < 4; ++ni) {
        int n = blockN + wn * 64 + ni * 16 + lr;
        int h = n >> 6, d = n & 63;
#pragma unroll
        for (int j = 0; j < 4; ++j) {
          int m = blockM + wm * 64 + mi * 16 + lg * 4 + j;
          int b = m >> 11, tq = m & 2047;
          size_t row = (size_t)b * TT + h * 128 + (tq >> 4);
          out[row * HID + (tq & 15) * 64 + d] = f2bf(acc[mi][ni][j]);
        }
      }
    }
  } else {
    float* out = (float*)outBase;
#pragma unroll
    for (int mi = 0; mi < 4; ++mi) {
#pragma unroll
      for (int ni = 0; ni < 4; ++ni) {
        int n = blockN + wn * 64 + ni * 16 + lr;
#pragma unroll
        for (int j = 0; j < 4; ++j) {
          int m = blockM + wm * 64 + mi * 16 + lg * 4 + j;
          out[(size_t)m * HID + n] = acc[mi][ni][j];
        }
      }
    }
  }
}

extern "C" void kernel_launch(void* const* d_in, const int* in_sizes, int n_in,
                              void* d_out, int out_size, void* d_ws, size_t ws_size,
                              hipStream_t stream) {
  const float* x = (const float*)d_in[0];
  // d_in[1] = mask: irrelevant — additive finite mask cannot change sum_l softmax = 1,
  // and the reference's einsum 'bhtl,bthd->bhtd' contracts l over A alone.
  // d_in[2] = Wq, d_in[3] = Wk: unused for the same reason.
  const float* Wv = (const float*)d_in[4];
  const float* Wo = (const float*)d_in[5];

  char* ws = (char*)d_ws;
  unsigned short* Mb  = (unsigned short*)(ws);                 // [0,16M): permuted ctx bf16
  unsigned short* wvt = (unsigned short*)(ws + (16u << 20));   // [16,18M): Wv^T bf16 [out][in]
  unsigned short* wob = (unsigned short*)(ws + (18u << 20));   // [18,20M): Wo bf16 ([out][in] already)

  prep_weights<<<dim3(32, 32, 2), dim3(32, 8), 0, stream>>>(Wv, Wo, wvt, wob);
  gemm_bk32<0><<<512, 256, 0, stream>>>(x, wvt, Mb);
  gemm_bk32<1><<<512, 256, 0, stream>>>(Mb, wob, d_out);
}